// Round 13
// baseline (2561.595 us; speedup 1.0000x reference)
//
#include <hip/hip_runtime.h>

typedef _Float16 half2v __attribute__((ext_vector_type(2)));
typedef _Float16 half8 __attribute__((ext_vector_type(8)));
typedef float floatx4 __attribute__((ext_vector_type(4)));

#define T_LEN 2048

// LDS-only barrier: waits ds ops, does NOT drain vmcnt (globals stay in flight)
#define LDS_BARRIER() asm volatile("s_waitcnt lgkmcnt(0)\n\ts_barrier" ::: "memory")

#if __has_builtin(__builtin_amdgcn_fdot2)
#define FDOT2(a, b, c) __builtin_amdgcn_fdot2((a), (b), (c), false)
#else
static __device__ inline float fdot2_fallback(half2v a, half2v b, float c) {
    return fmaf((float)a[1], (float)b[1], fmaf((float)a[0], (float)b[0], c));
}
#define FDOT2(a, b, c) fdot2_fallback((a), (b), (c))
#endif

// ---------------- Kernel 1: fused per-token table + Wh cast ----------------
__global__ __launch_bounds__(256) void precompute_k(
    const float* __restrict__ E, const float* __restrict__ Wx,
    const float* __restrict__ Wh, const float* __restrict__ Wz,
    float2* __restrict__ wgt, _Float16* __restrict__ Whf)
{
    const int v = blockIdx.x, e = threadIdx.x;
    __shared__ float Ev[256];
    Ev[e] = E[v * 256 + e];
    __syncthreads();
    float ax = 0.f, az = 0.f;
    #pragma unroll 4
    for (int d = 0; d < 256; d += 4) {
        float4 ev = *(const float4*)&Ev[d];
        float4 wx = *(const float4*)&Wx[e * 256 + d];
        float4 wz = *(const float4*)&Wz[e * 256 + d];
        ax += ev.x * wx.x + ev.y * wx.y + ev.z * wx.z + ev.w * wx.w;
        az += ev.x * wz.x + ev.y * wz.y + ev.z * wz.z + ev.w * wz.w;
    }
    float2 o; o.x = ax; o.y = 1.f / (1.f + __expf(-az));
    wgt[v * 256 + e] = o;
    Whf[v * 256 + e] = (_Float16)Wh[v * 256 + e];
}

// ---------------- Kernel 2: serial recurrence, 2 chains per wave ----------
// ROUND-9 LESSON: three Wh-residency fixes -> identical counters. Wh is NOT
// the bottleneck (spilled cheaply, likely AGPR). The step is LATENCY-bound:
// ~630cy VALU issue vs ~1325cy step at 1 wave/SIMD — ds_read/shuffle/barrier
// gaps idle the SIMD ~50%. Fix: run TWO independent batch recurrences in the
// SAME wave (32 WGs x 2 batches). Wh registers shared; chain B's VALU fills
// chain A's latency gaps and vice versa. One barrier per step serves both.
// Layout per batch unchanged: wave w owns dims [64w,64w+64); lane g=l&15,
// kq=l>>4 dots dims dbase..dbase+3 over k in [64kq,64kq+64) via fdot2;
// 2-round __shfl_xor(16,32) reduce; lane finishes dim dbase+kq; tanh
// epilogue, gated y-store, f16 h to LDS (padded k-quarters, conflict-free).
// wgt gathers prefetched 2 steps ahead into the consumed registers.
__global__ __launch_bounds__(256, 1) void rnn_k(
    const int* __restrict__ tokens, const float2* __restrict__ wgt,
    const _Float16* __restrict__ Whf, float* __restrict__ y)
{
    const int tid = threadIdx.x;
    const int w   = tid >> 6;                 // wave = output-dim chunk
    const int l   = tid & 63;
    const int g   = l & 15, kq = l >> 4;
    const int b0  = blockIdx.x << 1;          // batch A (B = b0+1)
    const int dbase = (w << 6) + (g << 2);    // first of 4 dims this lane dots
    const int k0    = kq << 6;                // k-range start (64 wide)
    const int dout  = dbase + kq;             // dim this lane finishes

// 32 NAMED Wh fragment registers: wh_j_c = Wh[dbase+j][k0+8c .. k0+8c+7]
#define WHV(j, c) wh_##j##_##c
#define DECL_WH(j, c)                                                          \
    half8 WHV(j, c) = *(const half8*)(Whf + (dbase + (j)) * 256 + k0 + ((c) << 3)); \
    asm volatile("" : "+v"(WHV(j, c)));
#define DECL_WH_ROW(j) \
    DECL_WH(j,0) DECL_WH(j,1) DECL_WH(j,2) DECL_WH(j,3) \
    DECL_WH(j,4) DECL_WH(j,5) DECL_WH(j,6) DECL_WH(j,7)
    DECL_WH_ROW(0) DECL_WH_ROW(1) DECL_WH_ROW(2) DECL_WH_ROW(3)

    // h per batch, double-buffered; k-quarters padded 64->72 f16 (144 B) so
    // the 4 kq broadcast-read groups land on disjoint banks.
    __shared__ __align__(16) _Float16 hb[2][2][4][72];   // [batch][buf][kq][..]
    __shared__ unsigned char tokL[2][T_LEN];

    for (int i = tid; i < 2 * T_LEN; i += 256) {
        const int hh = i >> 11, t = i & (T_LEN - 1);
        tokL[hh][t] = (unsigned char)tokens[(b0 + hh) * T_LEN + t];
    }
    for (int i = tid; i < 2 * 2 * 4 * 72; i += 256) ((_Float16*)hb)[i] = (_Float16)0.f;
    LDS_BARRIER();

    // y byte offsets: ((b*T + t)*256 + dout)*4, advance 1024 B per step
    unsigned int yoffA = (unsigned)(b0 * (T_LEN * 256) + dout) * 4u;
    unsigned int yoffB = (unsigned)((b0 + 1) * (T_LEN * 256) + dout) * 4u;

    // prologue: wx/gate for t=0 (even regs) and t=1 (odd regs), both batches
    float wxAe, gAe, wxAo, gAo, wxBe, gBe, wxBo, gBo;
    {
        float2 a = wgt[tokL[0][0] * 256 + dout]; wxAe = a.x; gAe = a.y;
        float2 c = wgt[tokL[0][1] * 256 + dout]; wxAo = c.x; gAo = c.y;
        float2 d = wgt[tokL[1][0] * 256 + dout]; wxBe = d.x; gBe = d.y;
        float2 e = wgt[tokL[1][1] * 256 + dout]; wxBo = e.x; gBo = e.y;
    }

// one k-pair (literal indices I0,I1) of Wh against both batches' h
#define DOT_PAIR(c, I0, I1)                                                    \
        {                                                                      \
            half2v hA = __builtin_shufflevector(hvA, hvA, I0, I1);             \
            half2v hB = __builtin_shufflevector(hvB, hvB, I0, I1);             \
            half2v w0 = __builtin_shufflevector(WHV(0,c), WHV(0,c), I0, I1);   \
            half2v w1 = __builtin_shufflevector(WHV(1,c), WHV(1,c), I0, I1);   \
            half2v w2 = __builtin_shufflevector(WHV(2,c), WHV(2,c), I0, I1);   \
            half2v w3 = __builtin_shufflevector(WHV(3,c), WHV(3,c), I0, I1);   \
            ac0 = FDOT2(w0, hA, ac0); bc0 = FDOT2(w0, hB, bc0);                \
            ac1 = FDOT2(w1, hA, ac1); bc1 = FDOT2(w1, hB, bc1);                \
            ac2 = FDOT2(w2, hA, ac2); bc2 = FDOT2(w2, hB, bc2);                \
            ac3 = FDOT2(w3, hA, ac3); bc3 = FDOT2(w3, hB, bc3);                \
        }

// all 4 k-pairs of LDS h-chunk c (literal c) for both batches
#define DOT_C(CUR, c)                                                          \
        {                                                                      \
            half8 hvA = *(const half8*)&hb[0][CUR][kq][(c) << 3];              \
            half8 hvB = *(const half8*)&hb[1][CUR][kq][(c) << 3];              \
            DOT_PAIR(c, 0, 1) DOT_PAIR(c, 2, 3)                                \
            DOT_PAIR(c, 4, 5) DOT_PAIR(c, 6, 7)                                \
        }

// finish one chain: reduce, select, tanh, gated store, h to LDS, wgt refill
#define FINISH(c0, c1, c2, c3, NXT, WX, G, YOFF, BI, tok)                      \
    {                                                                          \
        c0 += __shfl_xor(c0, 16); c0 += __shfl_xor(c0, 32);                    \
        c1 += __shfl_xor(c1, 16); c1 += __shfl_xor(c1, 32);                    \
        c2 += __shfl_xor(c2, 16); c2 += __shfl_xor(c2, 32);                    \
        c3 += __shfl_xor(c3, 16); c3 += __shfl_xor(c3, 32);                    \
        float s01 = (kq & 1) ? c1 : c0;                                        \
        float s23 = (kq & 1) ? c3 : c2;                                        \
        float sv  = (kq & 2) ? s23 : s01;                                      \
        float pre = sv + WX;                                                   \
        float ex  = __builtin_amdgcn_exp2f(pre * 2.885390082f);                \
        float hval = fmaf(__builtin_amdgcn_rcpf(ex + 1.f), -2.f, 1.f);         \
        __builtin_nontemporal_store(hval * G, (float*)((char*)y + YOFF));      \
        YOFF += 1024;                                                          \
        hb[BI][NXT][w][(g << 2) + kq] = (_Float16)hval;                        \
        { const float2* gp = wgt + (tok) * 256 + dout; float2 a = *gp;         \
          WX = a.x; G = a.y; }                                                 \
    }

// One timestep for BOTH batches. Reads hb[*][CUR], writes hb[*][NXT].
#define STEP(tcur, CUR, NXT, WXA, GA, WXB, GB)                                 \
    {                                                                          \
        int tf = (tcur) + 2; if (tf > T_LEN - 1) tf = T_LEN - 1;               \
        const int tokA = tokL[0][tf];                                          \
        const int tokB = tokL[1][tf];                                          \
        float ac0 = 0.f, ac1 = 0.f, ac2 = 0.f, ac3 = 0.f;                      \
        float bc0 = 0.f, bc1 = 0.f, bc2 = 0.f, bc3 = 0.f;                      \
        DOT_C(CUR, 0) DOT_C(CUR, 1) DOT_C(CUR, 2) DOT_C(CUR, 3)                \
        DOT_C(CUR, 4) DOT_C(CUR, 5) DOT_C(CUR, 6) DOT_C(CUR, 7)                \
        FINISH(ac0, ac1, ac2, ac3, NXT, WXA, GA, yoffA, 0, tokA)               \
        FINISH(bc0, bc1, bc2, bc3, NXT, WXB, GB, yoffB, 1, tokB)               \
        LDS_BARRIER();                                                         \
    }

    for (int t = 0; t < T_LEN; t += 2) {
        STEP(t,     0, 1, wxAe, gAe, wxBe, gBe)  // even: buf0 -> buf1
        STEP(t + 1, 1, 0, wxAo, gAo, wxBo, gBo)  // odd:  buf1 -> buf0
    }
#undef STEP
#undef FINISH
#undef DOT_C
#undef DOT_PAIR
#undef DECL_WH_ROW
#undef DECL_WH
#undef WHV
}

// ---------------- Kernel 3: tied head, in place ----------------
__device__ inline half8 cvt8(const float* p) {
    float4 u = *(const float4*)p;
    float4 w = *(const float4*)(p + 4);
    half8 r;
    r[0] = (_Float16)u.x; r[1] = (_Float16)u.y; r[2] = (_Float16)u.z; r[3] = (_Float16)u.w;
    r[4] = (_Float16)w.x; r[5] = (_Float16)w.y; r[6] = (_Float16)w.z; r[7] = (_Float16)w.w;
    return r;
}

__global__ __launch_bounds__(256) void logits_k(
    const float* __restrict__ E, float* __restrict__ io)
{
    const int tid = threadIdx.x;
    const int wv = tid >> 6;             // v-chunk base = wv*64
    const int l  = tid & 63;
    const int n  = l & 15, q = l >> 4;
    const int rowbase = blockIdx.x << 6; // 64 rows per WG
    const int k0base = q << 3;

    floatx4 acc[4][4];
    #pragma unroll
    for (int mt = 0; mt < 4; ++mt)
        #pragma unroll
        for (int tn = 0; tn < 4; ++tn) acc[mt][tn] = 0.f;

    #pragma unroll
    for (int ks = 0; ks < 8; ++ks) {
        const int k0 = (ks << 5) + k0base;
        half8 a[4], bfr[4];
        #pragma unroll
        for (int mt = 0; mt < 4; ++mt)
            a[mt] = cvt8(io + (rowbase + (mt << 4) + n) * 256 + k0);
        #pragma unroll
        for (int tn = 0; tn < 4; ++tn)
            bfr[tn] = cvt8(E + ((wv << 6) + (tn << 4) + n) * 256 + k0);
        #pragma unroll
        for (int mt = 0; mt < 4; ++mt)
            #pragma unroll
            for (int tn = 0; tn < 4; ++tn)
                acc[mt][tn] = __builtin_amdgcn_mfma_f32_16x16x32_f16(a[mt], bfr[tn], acc[mt][tn], 0, 0, 0);
    }
    __syncthreads();  // every wave's y reads complete before anyone overwrites
    #pragma unroll
    for (int mt = 0; mt < 4; ++mt)
        #pragma unroll
        for (int tn = 0; tn < 4; ++tn)
            #pragma unroll
            for (int r = 0; r < 4; ++r)
                io[(rowbase + (mt << 4) + (q << 2) + r) * 256 + (wv << 6) + (tn << 4) + n] = acc[mt][tn][r];
}

// ---------------- host ----------------
extern "C" void kernel_launch(void* const* d_in, const int* in_sizes, int n_in,
                              void* d_out, int out_size, void* d_ws, size_t ws_size,
                              hipStream_t stream) {
    const int*   tokens = (const int*)d_in[0];
    const float* E      = (const float*)d_in[1];
    const float* Wx     = (const float*)d_in[2];
    const float* Wh     = (const float*)d_in[3];
    const float* Wz     = (const float*)d_in[4];
    float* out = (float*)d_out;

    char* ws = (char*)d_ws;
    float2*   wgt = (float2*)ws;                      // 512 KiB
    _Float16* Whf = (_Float16*)(ws + (512 << 10));    // 128 KiB

    precompute_k<<<256, 256, 0, stream>>>(E, Wx, Wh, Wz, wgt, Whf);
    rnn_k<<<32, 256, 0, stream>>>(tokens, wgt, Whf, out);
    logits_k<<<2048, 256, 0, stream>>>(E, out);
}

// Round 19
// 1139.885 us; speedup vs baseline: 2.2472x; 2.2472x over previous
//
#include <hip/hip_runtime.h>

typedef _Float16 half2v __attribute__((ext_vector_type(2)));
typedef _Float16 half8 __attribute__((ext_vector_type(8)));
typedef float floatx4 __attribute__((ext_vector_type(4)));

#define T_LEN 2048

// LDS-only barrier: waits ds ops, does NOT drain vmcnt (globals stay in flight)
#define LDS_BARRIER() asm volatile("s_waitcnt lgkmcnt(0)\n\ts_barrier" ::: "memory")

#if __has_builtin(__builtin_amdgcn_fdot2)
#define FDOT2(a, b, c) __builtin_amdgcn_fdot2((a), (b), (c), false)
#else
static __device__ inline float fdot2_fallback(half2v a, half2v b, float c) {
    return fmaf((float)a[1], (float)b[1], fmaf((float)a[0], (float)b[0], c));
}
#define FDOT2(a, b, c) fdot2_fallback((a), (b), (c))
#endif

// butterfly-add with quad_perm DPP (pure VALU — no DS pipe).
// ctrl 0xB1 = quad_perm[1,0,3,2] (xor 1); 0x4E = quad_perm[2,3,0,1] (xor 2)
#define DPP_ADD(x, CTRL)                                                       \
    {                                                                          \
        int _s = __builtin_bit_cast(int, x);                                   \
        int _m = __builtin_amdgcn_update_dpp(0, _s, CTRL, 0xf, 0xf, true);     \
        x += __builtin_bit_cast(float, _m);                                    \
    }

// ---------------- Kernel 1: fused per-token table + Wh cast ----------------
__global__ __launch_bounds__(256) void precompute_k(
    const float* __restrict__ E, const float* __restrict__ Wx,
    const float* __restrict__ Wh, const float* __restrict__ Wz,
    float2* __restrict__ wgt, _Float16* __restrict__ Whf)
{
    const int v = blockIdx.x, e = threadIdx.x;
    __shared__ float Ev[256];
    Ev[e] = E[v * 256 + e];
    __syncthreads();
    float ax = 0.f, az = 0.f;
    #pragma unroll 4
    for (int d = 0; d < 256; d += 4) {
        float4 ev = *(const float4*)&Ev[d];
        float4 wx = *(const float4*)&Wx[e * 256 + d];
        float4 wz = *(const float4*)&Wz[e * 256 + d];
        ax += ev.x * wx.x + ev.y * wx.y + ev.z * wx.z + ev.w * wx.w;
        az += ev.x * wz.x + ev.y * wz.y + ev.z * wz.z + ev.w * wz.w;
    }
    float2 o; o.x = ax; o.y = 1.f / (1.f + __expf(-az));
    wgt[v * 256 + e] = o;
    Whf[v * 256 + e] = (_Float16)Wh[v * 256 + e];
}

// ---------------- Kernel 2: serial recurrence, low-bit k-split + DPP ------
// ROUND-13 LESSON: 2-chain in-wave ILP = exactly 2x time -> step is
// PIPE-PHASE-SERIALIZED (DS phases and VALU phases alternate in barrier
// lockstep; ~600cy/CU DS + ~640cy VALU add up, never overlap). Fix: take the
// DS pipe out of the steady state. k-split moved to LOW lane bits
// (kq = l&3, g = l>>2):
//   * reduce partners are lane^1/lane^2 -> 2 DPP quad_perm VALU adds per
//     acc replace 8 ds_swizzle DS ops (zero DS in the reduce);
//   * each ds_read_b128 of h now has only 4 distinct addresses (16-way
//     broadcast, 4 distinct banks) -> near-free vs 12cy each.
// 64 WGs x 1 batch, 256 threads (4 waves, 1/SIMD), round-7 config otherwise.
// Wave w owns dims [64w,64w+64); lane dots dims dbase..dbase+3 (dbase =
// 64w+4g) over k in [64kq,64kq+64) via fdot2; DPP reduce over the quad;
// lane finishes dim dbase+kq: tanh epilogue, gated y-store, f16 h to LDS
// (padded k-quarters). One LDS-only barrier per step; wgt row gather
// prefetched 2 steps ahead into the consumed registers.
__global__ __launch_bounds__(256, 1) void rnn_k(
    const int* __restrict__ tokens, const float2* __restrict__ wgt,
    const _Float16* __restrict__ Whf, float* __restrict__ y)
{
    const int tid = threadIdx.x;
    const int w   = tid >> 6;                 // wave = output-dim chunk
    const int l   = tid & 63;
    const int kq  = l & 3;                    // k-quarter (LOW bits -> DPP)
    const int g   = l >> 2;                   // dim group 0..15
    const int b   = blockIdx.x;               // global batch
    const int dbase = (w << 6) + (g << 2);    // first of 4 dims this lane dots
    const int k0    = kq << 6;                // k-range start (64 wide)
    const int dout  = dbase + kq;             // dim this lane finishes

// 32 NAMED Wh fragment registers: wh_j_c = Wh[dbase+j][k0+8c .. k0+8c+7]
#define WHV(j, c) wh_##j##_##c
#define DECL_WH(j, c)                                                          \
    half8 WHV(j, c) = *(const half8*)(Whf + (dbase + (j)) * 256 + k0 + ((c) << 3)); \
    asm volatile("" : "+v"(WHV(j, c)));
#define DECL_WH_ROW(j) \
    DECL_WH(j,0) DECL_WH(j,1) DECL_WH(j,2) DECL_WH(j,3) \
    DECL_WH(j,4) DECL_WH(j,5) DECL_WH(j,6) DECL_WH(j,7)
    DECL_WH_ROW(0) DECL_WH_ROW(1) DECL_WH_ROW(2) DECL_WH_ROW(3)

    // h double-buffered; k-quarters padded 64->72 f16 (144 B): the 4
    // broadcast-read address groups land on disjoint banks.
    __shared__ __align__(16) _Float16 hb[2][4][72];
    __shared__ unsigned char tokL[T_LEN];

    for (int i = tid; i < T_LEN; i += 256)
        tokL[i] = (unsigned char)tokens[b * T_LEN + i];
    for (int i = tid; i < 2 * 4 * 72; i += 256) ((_Float16*)hb)[i] = (_Float16)0.f;
    LDS_BARRIER();

    // y byte offset: ((b*T + t)*256 + dout)*4, advances 1024 B per step
    unsigned int yoff = (unsigned)(b * (T_LEN * 256) + dout) * 4u;

    // prologue: wx/gate for t=0 (even regs) and t=1 (odd regs)
    float wx_e, g_e, wx_o, g_o;
    {
        const int t0 = tokL[0], t1 = tokL[1];
        float2 a = wgt[t0 * 256 + dout]; wx_e = a.x; g_e = a.y;
        float2 c = wgt[t1 * 256 + dout]; wx_o = c.x; g_o = c.y;
    }

// one k-pair (literal indices I0,I1 of the half8) against all 4 dims
#define DOT_PAIR(c, I0, I1)                                                    \
        {                                                                      \
            half2v hp = __builtin_shufflevector(hv, hv, I0, I1);               \
            ac0 = FDOT2(__builtin_shufflevector(WHV(0,c), WHV(0,c), I0, I1), hp, ac0); \
            ac1 = FDOT2(__builtin_shufflevector(WHV(1,c), WHV(1,c), I0, I1), hp, ac1); \
            ac2 = FDOT2(__builtin_shufflevector(WHV(2,c), WHV(2,c), I0, I1), hp, ac2); \
            ac3 = FDOT2(__builtin_shufflevector(WHV(3,c), WHV(3,c), I0, I1), hp, ac3); \
        }

// all 4 k-pairs of LDS h-chunk c (literal c) against all 4 dims
#define DOT_C(CUR, c)                                                          \
        {                                                                      \
            half8 hv = *(const half8*)&hb[CUR][kq][(c) << 3];                  \
            DOT_PAIR(c, 0, 1) DOT_PAIR(c, 2, 3)                                \
            DOT_PAIR(c, 4, 5) DOT_PAIR(c, 6, 7)                                \
        }

// One timestep. Reads hb[CUR] (h_{t-1}), writes hb[NXT] (h_t). Consumes WX/G,
// then refills them IN PLACE for tcur+2 (first consumer two barriers later
// -> L2 gather latency fully covered).
#define STEP(tcur, CUR, NXT, WX, G)                                            \
    {                                                                          \
        int tf = (tcur) + 2; if (tf > T_LEN - 1) tf = T_LEN - 1;               \
        const int tok = tokL[tf];                                              \
        float ac0 = 0.f, ac1 = 0.f, ac2 = 0.f, ac3 = 0.f;                      \
        DOT_C(CUR, 0) DOT_C(CUR, 1) DOT_C(CUR, 2) DOT_C(CUR, 3)                \
        DOT_C(CUR, 4) DOT_C(CUR, 5) DOT_C(CUR, 6) DOT_C(CUR, 7)                \
        DPP_ADD(ac0, 0xB1) DPP_ADD(ac0, 0x4E)                                  \
        DPP_ADD(ac1, 0xB1) DPP_ADD(ac1, 0x4E)                                  \
        DPP_ADD(ac2, 0xB1) DPP_ADD(ac2, 0x4E)                                  \
        DPP_ADD(ac3, 0xB1) DPP_ADD(ac3, 0x4E)                                  \
        float s01 = (kq & 1) ? ac1 : ac0;                                      \
        float s23 = (kq & 1) ? ac3 : ac2;                                      \
        float sv  = (kq & 2) ? s23 : s01;                                      \
        float pre = sv + WX;                                                   \
        float ex  = __builtin_amdgcn_exp2f(pre * 2.885390082f);                \
        float hval = fmaf(__builtin_amdgcn_rcpf(ex + 1.f), -2.f, 1.f);         \
        __builtin_nontemporal_store(hval * G, (float*)((char*)y + yoff));      \
        yoff += 1024;                                                          \
        hb[NXT][w][(g << 2) + kq] = (_Float16)hval;                            \
        { const float2* gp = wgt + tok * 256 + dout; float2 a = *gp;           \
          WX = a.x; G = a.y; }                                                 \
        LDS_BARRIER();                                                         \
    }

    for (int t = 0; t < T_LEN; t += 2) {
        STEP(t,     0, 1, wx_e, g_e)   // even: h_{t-1} in buf0, h_t -> buf1
        STEP(t + 1, 1, 0, wx_o, g_o)   // odd:  h_t in buf1, h_{t+1} -> buf0
    }
#undef STEP
#undef DOT_C
#undef DOT_PAIR
#undef DECL_WH_ROW
#undef DECL_WH
#undef WHV
}

// ---------------- Kernel 3: tied head, in place ----------------
__device__ inline half8 cvt8(const float* p) {
    float4 u = *(const float4*)p;
    float4 w = *(const float4*)(p + 4);
    half8 r;
    r[0] = (_Float16)u.x; r[1] = (_Float16)u.y; r[2] = (_Float16)u.z; r[3] = (_Float16)u.w;
    r[4] = (_Float16)w.x; r[5] = (_Float16)w.y; r[6] = (_Float16)w.z; r[7] = (_Float16)w.w;
    return r;
}

__global__ __launch_bounds__(256) void logits_k(
    const float* __restrict__ E, float* __restrict__ io)
{
    const int tid = threadIdx.x;
    const int wv = tid >> 6;             // v-chunk base = wv*64
    const int l  = tid & 63;
    const int n  = l & 15, q = l >> 4;
    const int rowbase = blockIdx.x << 6; // 64 rows per WG
    const int k0base = q << 3;

    floatx4 acc[4][4];
    #pragma unroll
    for (int mt = 0; mt < 4; ++mt)
        #pragma unroll
        for (int tn = 0; tn < 4; ++tn) acc[mt][tn] = 0.f;

    #pragma unroll
    for (int ks = 0; ks < 8; ++ks) {
        const int k0 = (ks << 5) + k0base;
        half8 a[4], bfr[4];
        #pragma unroll
        for (int mt = 0; mt < 4; ++mt)
            a[mt] = cvt8(io + (rowbase + (mt << 4) + n) * 256 + k0);
        #pragma unroll
        for (int tn = 0; tn < 4; ++tn)
            bfr[tn] = cvt8(E + ((wv << 6) + (tn << 4) + n) * 256 + k0);
        #pragma unroll
        for (int mt = 0; mt < 4; ++mt)
            #pragma unroll
            for (int tn = 0; tn < 4; ++tn)
                acc[mt][tn] = __builtin_amdgcn_mfma_f32_16x16x32_f16(a[mt], bfr[tn], acc[mt][tn], 0, 0, 0);
    }
    __syncthreads();  // every wave's y reads complete before anyone overwrites
    #pragma unroll
    for (int mt = 0; mt < 4; ++mt)
        #pragma unroll
        for (int tn = 0; tn < 4; ++tn)
            #pragma unroll
            for (int r = 0; r < 4; ++r)
                io[(rowbase + (mt << 4) + (q << 2) + r) * 256 + (wv << 6) + (tn << 4) + n] = acc[mt][tn][r];
}

// ---------------- host ----------------
extern "C" void kernel_launch(void* const* d_in, const int* in_sizes, int n_in,
                              void* d_out, int out_size, void* d_ws, size_t ws_size,
                              hipStream_t stream) {
    const int*   tokens = (const int*)d_in[0];
    const float* E      = (const float*)d_in[1];
    const float* Wx     = (const float*)d_in[2];
    const float* Wh     = (const float*)d_in[3];
    const float* Wz     = (const float*)d_in[4];
    float* out = (float*)d_out;

    char* ws = (char*)d_ws;
    float2*   wgt = (float2*)ws;                      // 512 KiB
    _Float16* Whf = (_Float16*)(ws + (512 << 10));    // 128 KiB

    precompute_k<<<256, 256, 0, stream>>>(E, Wx, Wh, Wz, wgt, Whf);
    rnn_k<<<64, 256, 0, stream>>>(tokens, wgt, Whf, out);
    logits_k<<<2048, 256, 0, stream>>>(E, out);
}